// Round 4
// baseline (437.417 us; speedup 1.0000x reference)
//
#include <hip/hip_runtime.h>
#include <math.h>

#define TT 2048
#define NN 8192
#define HH 128
#define NB 1024        // 4 blocks/CU x 256 CUs -> co-resident by construction
#define BS 256
#define ARR_N 64       // arrival counters spread over 64 cachelines
#define ARR_STRIDE 32  // u32 stride between counters (128 B)

typedef float f4 __attribute__((ext_vector_type(4)));

// ---------------------------------------------------------------------------
// Two-level grid barrier.
//  arrive: 64 counters in distinct cachelines; block b adds to arrive[b&63].
//  block 0 wave 0 polls all 64 via lanes + __shfl_down reduce; when the
//  monotone sum reaches NB*epoch it publishes release=epoch (one line).
//  All other blocks read-spin on release with s_sleep.
//  clock64 timeouts on both spins: co-residency failure => wrong answer, not hang.
// ---------------------------------------------------------------------------
__device__ __forceinline__ void grid_barrier(unsigned* __restrict__ arrive,
                                             unsigned* __restrict__ release,
                                             int epoch) {
    __syncthreads();
    if (threadIdx.x == 0) {
        __threadfence();   // release my phase writes device-wide
        __hip_atomic_fetch_add(&arrive[(blockIdx.x & (ARR_N - 1)) * ARR_STRIDE], 1u,
                               __ATOMIC_RELEASE, __HIP_MEMORY_SCOPE_AGENT);
    }
    if (blockIdx.x == 0) {
        if (threadIdx.x < 64) {
            const unsigned target = (unsigned)(NB * epoch);
            const long long t0 = clock64();
            unsigned sum;
            do {
                unsigned v = __hip_atomic_load(&arrive[threadIdx.x * ARR_STRIDE],
                                               __ATOMIC_RELAXED, __HIP_MEMORY_SCOPE_AGENT);
                sum = v;
                #pragma unroll
                for (int off = 32; off >= 1; off >>= 1) sum += __shfl_down(sum, off, 64);
                sum = __shfl(sum, 0, 64);
                if (clock64() - t0 > 50000000LL) break;   // ~20 ms failsafe
            } while (sum < target);
            if (threadIdx.x == 0) {
                __threadfence();
                __hip_atomic_store(release, (unsigned)epoch,
                                   __ATOMIC_RELEASE, __HIP_MEMORY_SCOPE_AGENT);
            }
        }
        __syncthreads();
    } else {
        if (threadIdx.x == 0) {
            const long long t0 = clock64();
            while (__hip_atomic_load(release, __ATOMIC_RELAXED,
                                     __HIP_MEMORY_SCOPE_AGENT) < (unsigned)epoch) {
                __builtin_amdgcn_s_sleep(8);
                if (clock64() - t0 > 50000000LL) break;
            }
            __threadfence();   // acquire
        }
        __syncthreads();
    }
}

// Zero barrier state each launch (workspace is poisoned between iterations).
__global__ void init_kernel(unsigned* bar) {
    for (int i = threadIdx.x; i < (ARR_N + 1) * ARR_STRIDE; i += BS) bar[i] = 0u;
}

__device__ __forceinline__ void mm4(const float* __restrict__ A,
                                    const float* __restrict__ B,
                                    float* __restrict__ C) {
    #pragma unroll
    for (int i = 0; i < 4; ++i) {
        #pragma unroll
        for (int j = 0; j < 4; ++j) {
            float s = 0.0f;
            #pragma unroll
            for (int k = 0; k < 4; ++k) s = fmaf(A[i * 4 + k], B[k * 4 + j], s);
            C[i * 4 + j] = s;
        }
    }
}

// ---------------------------------------------------------------------------
// Fused pipeline: MLP -> cumsum -> expm -> apply, one dispatch, 3 barriers.
// ---------------------------------------------------------------------------
__global__ __launch_bounds__(BS, 4) void fused_kernel(
    const float* __restrict__ t_arr, const float* __restrict__ M0,
    const float* __restrict__ W1, const float* __restrict__ b1,
    const float* __restrict__ W2, const float* __restrict__ b2,
    const float* __restrict__ W3, const float* __restrict__ b3,
    const float* __restrict__ x, float* __restrict__ out,
    float* __restrict__ A_t, float* __restrict__ Asum,
    float* __restrict__ E, unsigned* __restrict__ arrive,
    unsigned* __restrict__ release)
{
    // ---- Phase 1: per-timestep MLP (2 timesteps per block) ----------------
    {
        const int tloc = threadIdx.x >> 7;           // 0..1
        const int j    = threadIdx.x & 127;          // 0..127
        const int t    = (blockIdx.x << 1) + tloc;   // 0..2047
        __shared__ float h1[2][HH];
        __shared__ float h2[2][HH];

        const float t_cur  = t_arr[t];
        const float t_prev = (t > 0) ? t_arr[t - 1] : 0.0f;
        const float dt = t_cur - t_prev;
        const float ta = 0.5f * (t_cur + t_prev);

        h1[tloc][j] = tanhf(fmaf(ta, W1[j], b1[j]));
        __syncthreads();

        float acc = b2[j];
        #pragma unroll 8
        for (int i = 0; i < HH; ++i) acc = fmaf(h1[tloc][i], W2[i * HH + j], acc);
        h2[tloc][j] = tanhf(acc);
        __syncthreads();

        if (j < 16) {
            float a = b3[j];
            #pragma unroll 8
            for (int i = 0; i < HH; ++i) a = fmaf(h2[tloc][i], W3[i * 16 + j], a);
            a = (a + M0[j]) * dt;
            A_t[j * TT + t] = a;    // transposed: contiguous per-element sequences
        }
    }
    grid_barrier(arrive, release, 1);

    // ---- Phase 2: cumsum over t. 16 blocks, one element each (wave 0). ----
    if (blockIdx.x < 16 && threadIdx.x < 64) {
        const int e    = blockIdx.x;
        const int lane = threadIdx.x;
        const float4* src = (const float4*)(A_t + e * TT + lane * 32);
        float4 v[8];
        float s = 0.0f;
        #pragma unroll
        for (int i = 0; i < 8; ++i) {
            v[i] = src[i];
            s += v[i].x + v[i].y + v[i].z + v[i].w;
        }
        float sc = s;
        #pragma unroll
        for (int d = 1; d < 64; d <<= 1) {
            const float up = __shfl_up(sc, d, 64);
            if (lane >= d) sc += up;
        }
        const float ex = __shfl_up(sc, 1, 64);
        float run = (lane == 0) ? 0.0f : ex;
        const int t0 = lane * 32;
        #pragma unroll
        for (int i = 0; i < 8; ++i) {
            run += v[i].x; Asum[(t0 + 4 * i + 0) * 16 + e] = run;
            run += v[i].y; Asum[(t0 + 4 * i + 1) * 16 + e] = run;
            run += v[i].z; Asum[(t0 + 4 * i + 2) * 16 + e] = run;
            run += v[i].w; Asum[(t0 + 4 * i + 3) * 16 + e] = run;
        }
    }
    grid_barrier(arrive, release, 2);

    // ---- Phase 3: batched 4x4 expm (blocks 0..7, one thread per t) --------
    if (blockIdx.x < 8) {
        const int t = blockIdx.x * BS + threadIdx.x;
        float M[16];
        const float4* src = (const float4*)(Asum + t * 16);
        #pragma unroll
        for (int r = 0; r < 4; ++r) {
            float4 v = src[r];
            M[r*4+0] = v.x; M[r*4+1] = v.y; M[r*4+2] = v.z; M[r*4+3] = v.w;
        }
        float nrm = 0.0f;
        #pragma unroll
        for (int i = 0; i < 4; ++i) {
            float rs = fabsf(M[i*4+0]) + fabsf(M[i*4+1]) + fabsf(M[i*4+2]) + fabsf(M[i*4+3]);
            nrm = fmaxf(nrm, rs);
        }
        int k = 0;
        while (nrm > 0.5f && k < 40) { nrm *= 0.5f; ++k; }
        const float sc = ldexpf(1.0f, -k);
        #pragma unroll
        for (int i = 0; i < 16; ++i) M[i] *= sc;

        float R[16], P[16], Q[16];
        #pragma unroll
        for (int i = 0; i < 16; ++i) { P[i] = M[i]; R[i] = M[i]; }
        R[0] += 1.0f; R[5] += 1.0f; R[10] += 1.0f; R[15] += 1.0f;
        for (int n = 2; n <= 12; ++n) {
            mm4(P, M, Q);
            const float inv = 1.0f / (float)n;
            #pragma unroll
            for (int i = 0; i < 16; ++i) { P[i] = Q[i] * inv; R[i] += P[i]; }
        }
        for (int s = 0; s < k; ++s) {
            mm4(R, R, Q);
            #pragma unroll
            for (int i = 0; i < 16; ++i) R[i] = Q[i];
        }
        float4* dst = (float4*)(E + t * 16);
        #pragma unroll
        for (int r = 0; r < 4; ++r)
            dst[r] = make_float4(R[r*4+0], R[r*4+1], R[r*4+2], R[r*4+3]);
    }
    grid_barrier(arrive, release, 3);

    // ---- Phase 4: out[t,n,:] = E[t] @ x[n]  (2 timesteps per block) -------
    {
        const f4* xs = (const f4*)x;
        #pragma unroll
        for (int tl = 0; tl < 2; ++tl) {
            const int t = (blockIdx.x << 1) + tl;
            const f4* Ev = (const f4*)(E + t * 16);
            const f4 e0 = Ev[0], e1 = Ev[1], e2 = Ev[2], e3 = Ev[3];
            f4* os = (f4*)out + (size_t)t * NN;
            for (int n = threadIdx.x; n < NN; n += BS) {
                const f4 xv = xs[n];
                f4 o;
                o.x = fmaf(e0.x, xv.x, fmaf(e0.y, xv.y, fmaf(e0.z, xv.z, e0.w * xv.w)));
                o.y = fmaf(e1.x, xv.x, fmaf(e1.y, xv.y, fmaf(e1.z, xv.z, e1.w * xv.w)));
                o.z = fmaf(e2.x, xv.x, fmaf(e2.y, xv.y, fmaf(e2.z, xv.z, e2.w * xv.w)));
                o.w = fmaf(e3.x, xv.x, fmaf(e3.y, xv.y, fmaf(e3.z, xv.z, e3.w * xv.w)));
                os[n] = o;   // plain stores: the proven 6.3+ TB/s path
            }
        }
    }
}

// ---------------------------------------------------------------------------
extern "C" void kernel_launch(void* const* d_in, const int* in_sizes, int n_in,
                              void* d_out, int out_size, void* d_ws, size_t ws_size,
                              hipStream_t stream) {
    const float* x  = (const float*)d_in[0];   // (N, D)
    const float* t  = (const float*)d_in[1];   // (T,)
    const float* M0 = (const float*)d_in[2];   // (D, D) zeros
    const float* W1 = (const float*)d_in[3];   // (1, H)
    const float* b1 = (const float*)d_in[4];   // (H,)
    const float* W2 = (const float*)d_in[5];   // (H, H)
    const float* b2 = (const float*)d_in[6];   // (H,)
    const float* W3 = (const float*)d_in[7];   // (H, 16)
    const float* b3 = (const float*)d_in[8];   // (16,)
    float* out = (float*)d_out;                // (T, N, D) f32

    float* A_t  = (float*)d_ws;                // 16*T floats (transposed)
    float* Asum = A_t  + 16 * TT;              // 16*T floats, (T,16)
    float* E    = Asum + 16 * TT;              // 16*T floats, (T,16)
    unsigned* bar = (unsigned*)(E + 16 * TT);  // 64 arrive counters + release
    unsigned* arrive  = bar;
    unsigned* release = bar + ARR_N * ARR_STRIDE;

    init_kernel<<<1, BS, 0, stream>>>(bar);
    fused_kernel<<<NB, BS, 0, stream>>>(t, M0, W1, b1, W2, b2, W3, b3,
                                        x, out, A_t, Asum, E, arrive, release);
}

// Round 5
// 297.591 us; speedup vs baseline: 1.4699x; 1.4699x over previous
//
#include <hip/hip_runtime.h>
#include <math.h>

#define TT 2048
#define NN 8192
#define HH 128

typedef float f4 __attribute__((ext_vector_type(4)));

// ---------------------------------------------------------------------------
// Stage 1: per-timestep MLP -> A, stored TRANSPOSED: A_t[m*TT + t], m in [0,16)
// One block per timestep, HH=128 threads. (proven in R3)
// ---------------------------------------------------------------------------
__global__ void mlp_kernel(const float* __restrict__ t_arr,
                           const float* __restrict__ M0,
                           const float* __restrict__ W1, const float* __restrict__ b1,
                           const float* __restrict__ W2, const float* __restrict__ b2,
                           const float* __restrict__ W3, const float* __restrict__ b3,
                           float* __restrict__ A_t) {
    const int t = blockIdx.x;
    const int j = threadIdx.x;
    __shared__ float h1[HH];
    __shared__ float h2[HH];

    const float t_cur  = t_arr[t];
    const float t_prev = (t > 0) ? t_arr[t - 1] : 0.0f;
    const float dt = t_cur - t_prev;
    const float ta = 0.5f * (t_cur + t_prev);

    h1[j] = tanhf(fmaf(ta, W1[j], b1[j]));
    __syncthreads();

    float acc = b2[j];
    #pragma unroll 8
    for (int i = 0; i < HH; ++i) acc = fmaf(h1[i], W2[i * HH + j], acc);
    h2[j] = tanhf(acc);
    __syncthreads();

    if (j < 16) {
        float a = b3[j];
        #pragma unroll 8
        for (int i = 0; i < HH; ++i) a = fmaf(h2[i], W3[i * 16 + j], a);
        a = (a + M0[j]) * dt;
        A_t[j * TT + t] = a;   // [entry][time] layout for contiguous scan loads
    }
}

// ---------------------------------------------------------------------------
// Stage 2+3 fused: cumsum + expm, NO cross-block sync.
// 16 blocks x 256 threads. Block b owns timesteps [128b, 128b+128).
// Each block REDUNDANTLY scans all 16 entry-sequences (A_t is 128 KB,
// L2-resident; redundancy is ~2 MB of L2 reads total — trivial) and keeps
// only its own 128-step slice in LDS. Then 128 threads run expm on the slice.
// ---------------------------------------------------------------------------
__device__ __forceinline__ void mm4(const float* __restrict__ A,
                                    const float* __restrict__ B,
                                    float* __restrict__ C) {
    #pragma unroll
    for (int i = 0; i < 4; ++i) {
        #pragma unroll
        for (int j = 0; j < 4; ++j) {
            float s = 0.0f;
            #pragma unroll
            for (int k = 0; k < 4; ++k) s = fmaf(A[i * 4 + k], B[k * 4 + j], s);
            C[i * 4 + j] = s;
        }
    }
}

__global__ __launch_bounds__(256) void scanexpm_kernel(const float* __restrict__ A_t,
                                                       float* __restrict__ E) {
    const int b    = blockIdx.x;        // 0..15: owns t in [128b, 128b+128)
    const int w    = threadIdx.x >> 6;  // wave 0..3
    const int lane = threadIdx.x & 63;  // chunk id: covers t in [32*lane, +32)

    __shared__ float As[128][17];       // [t_loc][entry], padded: conflict-free

    // ---- scan: wave w handles entries m = 4w..4w+3, serially ----
    #pragma unroll
    for (int r = 0; r < 4; ++r) {
        const int m = (w << 2) | r;
        const float4* src = (const float4*)(A_t + m * TT + lane * 32);
        float4 v[8];
        float s = 0.0f;
        #pragma unroll
        for (int i = 0; i < 8; ++i) {
            v[i] = src[i];
            s += v[i].x + v[i].y + v[i].z + v[i].w;
        }
        // inclusive wave scan of 64 chunk sums
        float sc = s;
        #pragma unroll
        for (int d = 1; d < 64; d <<= 1) {
            const float up = __shfl_up(sc, d, 64);
            if (lane >= d) sc += up;
        }
        // exclusive prefix for this chunk
        const float ex = __shfl_up(sc, 1, 64);
        float run = (lane == 0) ? 0.0f : ex;

        // only the 4 chunks inside this block's t-range materialize to LDS
        if ((lane >> 2) == b) {
            const int tl = (lane & 3) * 32;   // t_loc base
            #pragma unroll
            for (int i = 0; i < 8; ++i) {
                run += v[i].x; As[tl + 4*i + 0][m] = run;
                run += v[i].y; As[tl + 4*i + 1][m] = run;
                run += v[i].z; As[tl + 4*i + 2][m] = run;
                run += v[i].w; As[tl + 4*i + 3][m] = run;
            }
        }
    }
    __syncthreads();

    // ---- expm: 128 threads, one timestep each ----
    if (threadIdx.x < 128) {
        const int tl = threadIdx.x;
        const int t  = (b << 7) + tl;

        float M[16];
        #pragma unroll
        for (int i = 0; i < 16; ++i) M[i] = As[tl][i];

        // inf-norm (max abs row sum)
        float nrm = 0.0f;
        #pragma unroll
        for (int i = 0; i < 4; ++i) {
            float rs = fabsf(M[i*4+0]) + fabsf(M[i*4+1]) + fabsf(M[i*4+2]) + fabsf(M[i*4+3]);
            nrm = fmaxf(nrm, rs);
        }
        int k = 0;
        while (nrm > 0.5f && k < 40) { nrm *= 0.5f; ++k; }
        const float sc = ldexpf(1.0f, -k);
        #pragma unroll
        for (int i = 0; i < 16; ++i) M[i] *= sc;

        // Taylor: R = I + M + M^2/2! + ... + M^12/12!
        float R[16], P[16], Q[16];
        #pragma unroll
        for (int i = 0; i < 16; ++i) { P[i] = M[i]; R[i] = M[i]; }
        R[0] += 1.0f; R[5] += 1.0f; R[10] += 1.0f; R[15] += 1.0f;
        for (int n = 2; n <= 12; ++n) {
            mm4(P, M, Q);
            const float inv = 1.0f / (float)n;
            #pragma unroll
            for (int i = 0; i < 16; ++i) { P[i] = Q[i] * inv; R[i] += P[i]; }
        }
        for (int s = 0; s < k; ++s) {
            mm4(R, R, Q);
            #pragma unroll
            for (int i = 0; i < 16; ++i) R[i] = Q[i];
        }

        float4* dst = (float4*)(E + t * 16);
        #pragma unroll
        for (int r = 0; r < 4; ++r)
            dst[r] = make_float4(R[r*4+0], R[r*4+1], R[r*4+2], R[r*4+3]);
    }
}

// ---------------------------------------------------------------------------
// Stage 4: out[t,n,:] = E[t] @ x[n].  263 MB store stream. (proven in R3)
// grid (2, TT) = 4096 blocks x 256 threads; E[t] in registers (uniform loads),
// 16 independent float4 load/store iterations per thread. Plain stores.
// ---------------------------------------------------------------------------
__global__ __launch_bounds__(256) void apply_kernel(const float* __restrict__ E,
                                                    const float* __restrict__ x,
                                                    float* __restrict__ out) {
    const int t = blockIdx.y;
    const int nbase = blockIdx.x * (NN / 2);

    const f4* Ev = (const f4*)(E + t * 16);
    const f4 e0 = Ev[0], e1 = Ev[1], e2 = Ev[2], e3 = Ev[3];

    const f4* xs = (const f4*)x + nbase;
    f4* os = (f4*)out + (size_t)t * NN + nbase;

    #pragma unroll 4
    for (int n = threadIdx.x; n < NN / 2; n += 256) {
        const f4 xv = xs[n];
        f4 o;
        o.x = fmaf(e0.x, xv.x, fmaf(e0.y, xv.y, fmaf(e0.z, xv.z, e0.w * xv.w)));
        o.y = fmaf(e1.x, xv.x, fmaf(e1.y, xv.y, fmaf(e1.z, xv.z, e1.w * xv.w)));
        o.z = fmaf(e2.x, xv.x, fmaf(e2.y, xv.y, fmaf(e2.z, xv.z, e2.w * xv.w)));
        o.w = fmaf(e3.x, xv.x, fmaf(e3.y, xv.y, fmaf(e3.z, xv.z, e3.w * xv.w)));
        os[n] = o;
    }
}

// ---------------------------------------------------------------------------
extern "C" void kernel_launch(void* const* d_in, const int* in_sizes, int n_in,
                              void* d_out, int out_size, void* d_ws, size_t ws_size,
                              hipStream_t stream) {
    const float* x  = (const float*)d_in[0];   // (N, D)
    const float* t  = (const float*)d_in[1];   // (T,)
    const float* M0 = (const float*)d_in[2];   // (D, D) zeros
    const float* W1 = (const float*)d_in[3];   // (1, H)
    const float* b1 = (const float*)d_in[4];   // (H,)
    const float* W2 = (const float*)d_in[5];   // (H, H)
    const float* b2 = (const float*)d_in[6];   // (H,)
    const float* W3 = (const float*)d_in[7];   // (H, 16)
    const float* b3 = (const float*)d_in[8];   // (16,)
    float* out = (float*)d_out;                // (T, N, D) f32

    float* A_t = (float*)d_ws;                 // 16*T floats ([entry][time])
    float* E   = A_t + 16 * TT;                // 16*T floats, (T,16)

    mlp_kernel<<<TT, HH, 0, stream>>>(t, M0, W1, b1, W2, b2, W3, b3, A_t);
    scanexpm_kernel<<<16, 256, 0, stream>>>(A_t, E);
    apply_kernel<<<dim3(2, TT), 256, 0, stream>>>(E, x, out);
}